// Round 4
// baseline (386.523 us; speedup 1.0000x reference)
//
#include <hip/hip_runtime.h>
#include <hip/hip_bf16.h>

// StencilNet round 3: mids rebuilt as L2-direct implicit GEMM on
// mfma_f32_32x32x16_bf16: no act LDS (A-frags straight from global, L2-served),
// all-tap weights packed once in 72KB LDS (zero tap-loop barriers),
// 2 blocks/CU, XCD-chunked block swizzle. layer0/k_out unchanged (verified).

#define HW   256
#define MASK 255
#define CH   64
#define TX   32
#define TY   16

typedef short bf16x8 __attribute__((ext_vector_type(8)));
typedef float f32x4  __attribute__((ext_vector_type(4)));
typedef float f32x16 __attribute__((ext_vector_type(16)));

__device__ __forceinline__ float bf2f(unsigned short u) {
    return __uint_as_float(((unsigned int)u) << 16);
}
__device__ __forceinline__ unsigned short f2bf(float f) {
    unsigned int x = __float_as_uint(f);
    return (unsigned short)((x + 0x7fffu + ((x >> 16) & 1u)) >> 16);  // RNE
}

// ---------------- Layer 0: [C,vx,vy] (3ch f32) -> 64ch bf16, ReLU -------------
__global__ __launch_bounds__(512) void k_layer0(
    const float* __restrict__ Cin, const float* __restrict__ vx,
    const float* __restrict__ vy, const float* __restrict__ w0,
    const float* __restrict__ b0, unsigned short* __restrict__ out)
{
    int t  = threadIdx.x;
    int lx = t & 31, ly = t >> 5;
    int x  = blockIdx.x * TX + lx;
    int y  = blockIdx.y * TY + ly;
    int bb = blockIdx.z;
    int pbase = bb * HW * HW;

    float a[27];
#pragma unroll
    for (int ky = 0; ky < 3; ky++) {
        int yy = (y + ky - 1) & MASK;
#pragma unroll
        for (int kx = 0; kx < 3; kx++) {
            int xx  = (x + kx - 1) & MASK;
            int idx = pbase + yy * HW + xx;
            a[(ky * 3 + kx) * 3 + 0] = Cin[idx];
            a[(ky * 3 + kx) * 3 + 1] = vx[idx];
            a[(ky * 3 + kx) * 3 + 2] = vy[idx];
        }
    }

    size_t obase = ((size_t)(pbase + y * HW + x)) * CH;
    for (int c4 = 0; c4 < 4; c4++) {
        float acc[16];
#pragma unroll
        for (int j = 0; j < 16; j++) acc[j] = b0[c4 * 16 + j];
#pragma unroll
        for (int k = 0; k < 27; k++) {
            float av = a[k];
            const float* wq = w0 + k * CH + c4 * 16;
#pragma unroll
            for (int j = 0; j < 16; j++) acc[j] = fmaf(av, wq[j], acc[j]);
        }
        unsigned short o[16];
#pragma unroll
        for (int j = 0; j < 16; j++) o[j] = f2bf(fmaxf(acc[j], 0.f));
        *reinterpret_cast<uint4*>(out + obase + c4 * 16)     = *reinterpret_cast<uint4*>(o);
        *reinterpret_cast<uint4*>(out + obase + c4 * 16 + 8) = *reinterpret_cast<uint4*>(o + 8);
    }
}

// -------- Mid layers, L2-direct MFMA 32x32x16: 64ch bf16 -> 64ch, ReLU -------
// Block: 16x32 px tile, 8 waves; wave = 2 rows x 32 px, full co=64.
// A-frags: global loads (per-lane wrap). B-frags: all 9 taps in LDS (72 KB).
__global__ __launch_bounds__(512, 2) void k_mid_l2(
    const unsigned short* __restrict__ in, const float* __restrict__ w,
    const float* __restrict__ b, unsigned short* __restrict__ out)
{
    __shared__ unsigned short sW[4608 * 8];   // 73728 B

    const int t    = threadIdx.x;
    const int lane = t & 63;
    const int wv   = t >> 6;        // 0..7
    const int l31  = lane & 31;
    const int l5   = lane >> 5;     // 0..1

    // swizzled block -> tile (XCD k gets 128 consecutive tiles; 1024 % 8 == 0)
    const int bid = blockIdx.x;
    const int tid = (bid & 7) * 128 + (bid >> 3);
    const int bz  = tid >> 7;
    const int rr  = tid & 127;
    const int y0  = (rr >> 3) * 16;
    const int x0  = (rr & 7) * 32;
    const size_t pbase = (size_t)bz * HW * HW;

    // ---- stage all weights as 32x32x16 B-frags ----
    // granule g: tap=g>>9, k=(g>>7)&3, n=(g>>6)&1, l=g&63
    // value j = w[(tap*64 + k*16 + (l>>5)*8 + j)*64 + n*32 + (l&31)]
    for (int g = t; g < 4608; g += 512) {
        int gl = g & 63, gn = (g >> 6) & 1, gk = (g >> 7) & 3, gtap = g >> 9;
        const float* wp = w + (gtap * 64 + gk * 16 + ((gl >> 5) << 3)) * 64
                            + gn * 32 + (gl & 31);
        unsigned short o8[8];
#pragma unroll
        for (int j = 0; j < 8; j++) o8[j] = f2bf(wp[j * 64]);
        *reinterpret_cast<uint4*>(&sW[g * 8]) = *reinterpret_cast<uint4*>(o8);
    }
    __syncthreads();

    // ---- accumulators: C/D col = lane&31 = co within n-frag ----
    f32x16 acc[2][2];
    {
        float bv0 = b[l31], bv1 = b[32 + l31];
#pragma unroll
        for (int m = 0; m < 2; m++)
#pragma unroll
            for (int j = 0; j < 16; j++) {
                acc[m][0][j] = bv0;
                acc[m][1][j] = bv1;
            }
    }

    // per-lane x offsets (ushort units) for kx = 0,1,2; includes l5 ci-octet
    int xoff[3];
#pragma unroll
    for (int kx = 0; kx < 3; kx++)
        xoff[kx] = ((x0 + l31 + kx - 1) & MASK) * CH + l5 * 8;

    const unsigned short* inb = in + pbase * CH;

#pragma unroll
    for (int tap = 0; tap < 9; tap++) {
        const int ky = tap / 3, kx = tap % 3;
        const unsigned short* r0 =
            inb + (size_t)((y0 + 2 * wv + 0 + ky - 1) & MASK) * (HW * CH);
        const unsigned short* r1 =
            inb + (size_t)((y0 + 2 * wv + 1 + ky - 1) & MASK) * (HW * CH);
#pragma unroll
        for (int k = 0; k < 4; k++) {
            bf16x8 a0 = *reinterpret_cast<const bf16x8*>(r0 + xoff[kx] + k * 16);
            bf16x8 a1 = *reinterpret_cast<const bf16x8*>(r1 + xoff[kx] + k * 16);
            bf16x8 b0 = *reinterpret_cast<const bf16x8*>(
                &sW[(((tap * 4 + k) * 2 + 0) * 64 + lane) * 8]);
            bf16x8 b1 = *reinterpret_cast<const bf16x8*>(
                &sW[(((tap * 4 + k) * 2 + 1) * 64 + lane) * 8]);
            acc[0][0] = __builtin_amdgcn_mfma_f32_32x32x16_bf16(a0, b0, acc[0][0], 0, 0, 0);
            acc[0][1] = __builtin_amdgcn_mfma_f32_32x32x16_bf16(a0, b1, acc[0][1], 0, 0, 0);
            acc[1][0] = __builtin_amdgcn_mfma_f32_32x32x16_bf16(a1, b0, acc[1][0], 0, 0, 0);
            acc[1][1] = __builtin_amdgcn_mfma_f32_32x32x16_bf16(a1, b1, acc[1][1], 0, 0, 0);
        }
    }

    // ---- epilogue: ReLU -> bf16; C/D row = (reg&3)+8*(reg>>2)+4*l5 = px x ----
#pragma unroll
    for (int m = 0; m < 2; m++) {
        const int y = y0 + 2 * wv + m;
        unsigned short* ob = out + (pbase + (size_t)y * HW + x0) * CH + l31;
#pragma unroll
        for (int n = 0; n < 2; n++)
#pragma unroll
            for (int r4 = 0; r4 < 4; r4++)
#pragma unroll
                for (int j = 0; j < 4; j++) {
                    int r = j + 8 * r4 + 4 * l5;
                    ob[r * CH + n * 32] = f2bf(fmaxf(acc[m][n][r4 * 4 + j], 0.f));
                }
    }
}

// -------- Output layer MFMA: 64ch -> 16 coeffs + fused 4x4 stencil dot -------
__global__ __launch_bounds__(512, 2) void k_out_mfma(
    const unsigned short* __restrict__ in, const float* __restrict__ w,
    const float* __restrict__ b, const float* __restrict__ Cin,
    float* __restrict__ out)
{
    __shared__ unsigned short sAct[18 * 34 * CH];   // 78336 B
    __shared__ unsigned short sW[9 * 128 * 8];      // 18432 B
    __shared__ float sC[19 * 35];                   // 2660 B

    const int t    = threadIdx.x;
    const int lane = t & 63;
    const int wid  = t >> 6;
    const int l15  = lane & 15;
    const int l4   = lane >> 4;
    const int x0   = blockIdx.x * 32;
    const int y0   = blockIdx.y * 16;
    const size_t pbase = (size_t)blockIdx.z * HW * HW;

    for (int g = t; g < 18 * 34 * 8; g += 512) {
        int hp = g >> 3, cg = g & 7;
        int hr = hp / 34, hc = hp - hr * 34;
        int gy = (y0 + hr - 1) & MASK;
        int gx = (x0 + hc - 1) & MASK;
        uint4 v = *reinterpret_cast<const uint4*>(
            in + ((pbase + gy * HW + gx) * CH + cg * 8));
        *reinterpret_cast<uint4*>(&sAct[hp * 64 + ((cg ^ (hp & 7)) << 3)]) = v;
    }
    for (int g = t; g < 1152; g += 512) {
        int tap = g >> 7, s = (g >> 6) & 1, dl = g & 63;
        int ci0 = s * 32 + (dl >> 4) * 8;
        int co  = dl & 15;
        unsigned short o8[8];
#pragma unroll
        for (int j = 0; j < 8; j++)
            o8[j] = f2bf(w[(tap * 64 + ci0 + j) * 16 + co]);
        *reinterpret_cast<uint4*>(&sW[g * 8]) = *reinterpret_cast<uint4*>(o8);
    }
    for (int g = t; g < 19 * 35; g += 512) {
        int r = g / 35, c2 = g - r * 35;
        int gy = (y0 + r - 2) & MASK;
        int gx = (x0 + c2 - 2) & MASK;
        sC[g] = Cin[pbase + gy * HW + gx];
    }
    __syncthreads();

    f32x4 acc[4];
    {
        float bv = b[l15];
#pragma unroll
        for (int m = 0; m < 4; m++) acc[m] = (f32x4){bv, bv, bv, bv};
    }

    int pxb[4];
#pragma unroll
    for (int m = 0; m < 4; m++)
        pxb[m] = (2 * wid + (m >> 1)) * 34 + (m & 1) * 16 + l15;

    for (int tap = 0; tap < 9; tap++) {
        const int koff = (tap / 3) * 34 + (tap % 3);
#pragma unroll
        for (int s = 0; s < 2; s++) {
            bf16x8 bf = *reinterpret_cast<const bf16x8*>(
                &sW[((tap * 2 + s) << 9) + (lane << 3)]);
            const int o = s * 4 + l4;
#pragma unroll
            for (int m = 0; m < 4; m++) {
                int px  = pxb[m] + koff;
                int off = (px << 6) + (((o ^ px) & 7) << 3);
                bf16x8 af = *reinterpret_cast<const bf16x8*>(&sAct[off]);
                acc[m] = __builtin_amdgcn_mfma_f32_16x16x32_bf16(
                    af, bf, acc[m], 0, 0, 0);
            }
        }
    }

#pragma unroll
    for (int m = 0; m < 4; m++) {
        int py = 2 * wid + (m >> 1);
        int xb = (m & 1) * 16 + l4 * 4;
#pragma unroll
        for (int j = 0; j < 4; j++) {
            int xt = xb + j;
            float v = acc[m][j] * sC[(py + (l15 >> 2)) * 35 + xt + (l15 & 3)];
            v += __shfl_xor(v, 1);
            v += __shfl_xor(v, 2);
            v += __shfl_xor(v, 4);
            v += __shfl_xor(v, 8);
            if (l15 == 0)
                out[pbase + (y0 + py) * HW + x0 + xt] = v;
        }
    }
}

extern "C" void kernel_launch(void* const* d_in, const int* in_sizes, int n_in,
                              void* d_out, int out_size, void* d_ws, size_t ws_size,
                              hipStream_t stream)
{
    (void)in_sizes; (void)n_in; (void)out_size; (void)ws_size;
    const float* Cin  = (const float*)d_in[0];
    const float* vx   = (const float*)d_in[1];
    const float* vy   = (const float*)d_in[2];
    const float* w0   = (const float*)d_in[3];
    const float* b0   = (const float*)d_in[4];
    const float* w1   = (const float*)d_in[5];
    const float* b1   = (const float*)d_in[6];
    const float* w2   = (const float*)d_in[7];
    const float* b2   = (const float*)d_in[8];
    const float* w3   = (const float*)d_in[9];
    const float* b3   = (const float*)d_in[10];
    const float* w4   = (const float*)d_in[11];
    const float* b4   = (const float*)d_in[12];
    const float* wout = (const float*)d_in[13];
    const float* bout = (const float*)d_in[14];

    unsigned short* actA = (unsigned short*)d_ws;
    unsigned short* actB = actA + (size_t)8 * HW * HW * CH;

    dim3 block(512);
    dim3 grid0(HW / TX, HW / TY, 8);
    dim3 gridM(1024);
    dim3 gridO(HW / 32, HW / 16, 8);

    k_layer0  <<<grid0, block, 0, stream>>>(Cin, vx, vy, w0, b0, actA);
    k_mid_l2  <<<gridM, block, 0, stream>>>(actA, w1, b1, actB);
    k_mid_l2  <<<gridM, block, 0, stream>>>(actB, w2, b2, actA);
    k_mid_l2  <<<gridM, block, 0, stream>>>(actA, w3, b3, actB);
    k_mid_l2  <<<gridM, block, 0, stream>>>(actB, w4, b4, actA);
    k_out_mfma<<<gridO, block, 0, stream>>>(actA, wout, bout, Cin, (float*)d_out);
}

// Round 5
// 264.954 us; speedup vs baseline: 1.4588x; 1.4588x over previous
//
#include <hip/hip_runtime.h>
#include <hip/hip_bf16.h>

// StencilNet round 4: back to R2's verified LDS-act MFMA structure for mids,
// minus all weight-staging barriers: weights pre-packed once (k_pack) into
// B-frag layout in global scratch (parked in d_out, overwritten by k_out),
// loaded per-tap from L2 with register prefetch. 1 barrier per mid block.

#define HW   256
#define MASK 255
#define CH   64
#define TX   32
#define TY   16

typedef short bf16x8 __attribute__((ext_vector_type(8)));
typedef float f32x4  __attribute__((ext_vector_type(4)));

__device__ __forceinline__ float bf2f(unsigned short u) {
    return __uint_as_float(((unsigned int)u) << 16);
}
__device__ __forceinline__ unsigned short f2bf(float f) {
    unsigned int x = __float_as_uint(f);
    return (unsigned short)((x + 0x7fffu + ((x >> 16) & 1u)) >> 16);  // RNE
}

// ---- pack mid-layer weights into 16x16x32 B-frag layout (bf16) -------------
// granule r in [0,4608) per layer: q=r>>8 (tap*2+s), n=(r>>6)&3, l=r&63
// dst[L*36864 + r*8 + j] = w_L[(tap*64 + s*32 + (l>>4)*8 + j)*64 + n*16 + (l&15)]
__global__ __launch_bounds__(512) void k_pack(
    const float* __restrict__ w1, const float* __restrict__ w2,
    const float* __restrict__ w3, const float* __restrict__ w4,
    unsigned short* __restrict__ dst)
{
    int g = blockIdx.x * 512 + threadIdx.x;
    if (g >= 4 * 4608) return;
    int L = g / 4608, r = g - L * 4608;
    const float* w = (L == 0) ? w1 : (L == 1) ? w2 : (L == 2) ? w3 : w4;
    int q = r >> 8, n = (r >> 6) & 3, l = r & 63;
    int tap = q >> 1, s = q & 1;
    int ci0 = s * 32 + ((l >> 4) << 3);
    int co  = n * 16 + (l & 15);
    unsigned short o8[8];
#pragma unroll
    for (int j = 0; j < 8; j++)
        o8[j] = f2bf(w[(tap * 64 + ci0 + j) * 64 + co]);
    *reinterpret_cast<uint4*>(dst + (size_t)g * 8) = *reinterpret_cast<uint4*>(o8);
}

// ---------------- Layer 0: [C,vx,vy] (3ch f32) -> 64ch bf16, ReLU -------------
__global__ __launch_bounds__(512) void k_layer0(
    const float* __restrict__ Cin, const float* __restrict__ vx,
    const float* __restrict__ vy, const float* __restrict__ w0,
    const float* __restrict__ b0, unsigned short* __restrict__ out)
{
    int t  = threadIdx.x;
    int lx = t & 31, ly = t >> 5;
    int x  = blockIdx.x * TX + lx;
    int y  = blockIdx.y * TY + ly;
    int bb = blockIdx.z;
    int pbase = bb * HW * HW;

    float a[27];
#pragma unroll
    for (int ky = 0; ky < 3; ky++) {
        int yy = (y + ky - 1) & MASK;
#pragma unroll
        for (int kx = 0; kx < 3; kx++) {
            int xx  = (x + kx - 1) & MASK;
            int idx = pbase + yy * HW + xx;
            a[(ky * 3 + kx) * 3 + 0] = Cin[idx];
            a[(ky * 3 + kx) * 3 + 1] = vx[idx];
            a[(ky * 3 + kx) * 3 + 2] = vy[idx];
        }
    }

    size_t obase = ((size_t)(pbase + y * HW + x)) * CH;
    for (int c4 = 0; c4 < 4; c4++) {
        float acc[16];
#pragma unroll
        for (int j = 0; j < 16; j++) acc[j] = b0[c4 * 16 + j];
#pragma unroll
        for (int k = 0; k < 27; k++) {
            float av = a[k];
            const float* wq = w0 + k * CH + c4 * 16;
#pragma unroll
            for (int j = 0; j < 16; j++) acc[j] = fmaf(av, wq[j], acc[j]);
        }
        unsigned short o[16];
#pragma unroll
        for (int j = 0; j < 16; j++) o[j] = f2bf(fmaxf(acc[j], 0.f));
        *reinterpret_cast<uint4*>(out + obase + c4 * 16)     = *reinterpret_cast<uint4*>(o);
        *reinterpret_cast<uint4*>(out + obase + c4 * 16 + 8) = *reinterpret_cast<uint4*>(o + 8);
    }
}

// ------------- Mid layers, MFMA, barrier-free tap loop -----------------------
// Block: 32x32 px tile, 8 waves. Wave: 128 px (8 M-frags) x 64 co (4 N-frags).
// Act halo 34x34x64 bf16 in LDS (XOR swizzle, verified). B-frags from packed
// global (L2-hot), register-prefetched one (tap,s) step ahead.
#define MT 32

__global__ __launch_bounds__(512, 2) void k_mid_v4(
    const unsigned short* __restrict__ in,
    const unsigned short* __restrict__ wp,   // packed B-frags for this layer
    const float* __restrict__ b, unsigned short* __restrict__ out)
{
    __shared__ unsigned short sAct[34 * 34 * CH];  // 147968 B

    const int t    = threadIdx.x;
    const int lane = t & 63;
    const int wid  = t >> 6;
    const int l15  = lane & 15;
    const int l4   = lane >> 4;

    // bijective XCD-chunked swizzle: 512 blocks, 8 chunks of 64
    const int bid = blockIdx.x;
    const int tid = (bid & 7) * 64 + (bid >> 3);
    const int bz  = tid >> 6;          // image
    const int rr  = tid & 63;          // 8x8 tiles
    const int y0  = (rr >> 3) * MT;
    const int x0  = (rr & 7) * MT;
    const size_t pbase = (size_t)bz * HW * HW;

    // ---- stage act halo 34x34x64 (bf16), XOR-swizzled (verified R2) ----
    for (int g = t; g < 34 * 34 * 8; g += 512) {
        int hp = g >> 3, cg = g & 7;
        int hr = hp / 34, hc = hp - hr * 34;
        int gy = (y0 + hr - 1) & MASK;
        int gx = (x0 + hc - 1) & MASK;
        uint4 v = *reinterpret_cast<const uint4*>(
            in + ((pbase + gy * HW + gx) * CH + cg * 8));
        *reinterpret_cast<uint4*>(&sAct[hp * 64 + ((cg ^ (hp & 7)) << 3)]) = v;
    }

    // prefetch B-frags for q=0 while staging completes
    bf16x8 bnx[4];
#pragma unroll
    for (int n = 0; n < 4; n++)
        bnx[n] = *reinterpret_cast<const bf16x8*>(wp + (size_t)(n * 512 + lane * 8));

    __syncthreads();   // the only barrier

    f32x4 acc[8][4];
#pragma unroll
    for (int m = 0; m < 8; m++)
#pragma unroll
        for (int n = 0; n < 4; n++) {
            float bv = b[n * 16 + l15];
            acc[m][n] = (f32x4){bv, bv, bv, bv};
        }

    int pxb[8];
#pragma unroll
    for (int m = 0; m < 8; m++)
        pxb[m] = (4 * wid + (m >> 1)) * 34 + (m & 1) * 16 + l15;

#pragma unroll
    for (int tap = 0; tap < 9; tap++) {
        const int koff = (tap / 3) * 34 + (tap % 3);
#pragma unroll
        for (int s = 0; s < 2; s++) {
            const int q = tap * 2 + s;
            bf16x8 bc[4];
#pragma unroll
            for (int n = 0; n < 4; n++) bc[n] = bnx[n];
            if (q < 17) {
#pragma unroll
                for (int n = 0; n < 4; n++)
                    bnx[n] = *reinterpret_cast<const bf16x8*>(
                        wp + (size_t)(((q + 1) * 4 + n) * 512 + lane * 8));
            }
            const int o = s * 4 + l4;
#pragma unroll
            for (int m = 0; m < 8; m++) {
                int px  = pxb[m] + koff;
                int off = (px << 6) + (((o ^ px) & 7) << 3);
                bf16x8 af = *reinterpret_cast<const bf16x8*>(&sAct[off]);
#pragma unroll
                for (int n = 0; n < 4; n++)
                    acc[m][n] = __builtin_amdgcn_mfma_f32_16x16x32_bf16(
                        af, bc[n], acc[m][n], 0, 0, 0);
            }
        }
    }

    // ---- epilogue (verified R2) ----
#pragma unroll
    for (int m = 0; m < 8; m++) {
        int y = y0 + 4 * wid + (m >> 1);
        int x = x0 + (m & 1) * 16;
        unsigned short* pm = out + (pbase + (size_t)y * HW + x) * CH + (l4 << 8) + l15;
#pragma unroll
        for (int n = 0; n < 4; n++)
#pragma unroll
            for (int j = 0; j < 4; j++)
                pm[j * 64 + n * 16] = f2bf(fmaxf(acc[m][n][j], 0.f));
    }
}

// -------- Output layer MFMA: 64ch -> 16 coeffs + fused 4x4 stencil dot -------
__global__ __launch_bounds__(512, 2) void k_out_mfma(
    const unsigned short* __restrict__ in, const float* __restrict__ w,
    const float* __restrict__ b, const float* __restrict__ Cin,
    float* __restrict__ out)
{
    __shared__ unsigned short sAct[18 * 34 * CH];   // 78336 B
    __shared__ unsigned short sW[9 * 128 * 8];      // 18432 B
    __shared__ float sC[19 * 35];                   // 2660 B

    const int t    = threadIdx.x;
    const int lane = t & 63;
    const int wid  = t >> 6;
    const int l15  = lane & 15;
    const int l4   = lane >> 4;
    const int x0   = blockIdx.x * 32;
    const int y0   = blockIdx.y * 16;
    const size_t pbase = (size_t)blockIdx.z * HW * HW;

    for (int g = t; g < 18 * 34 * 8; g += 512) {
        int hp = g >> 3, cg = g & 7;
        int hr = hp / 34, hc = hp - hr * 34;
        int gy = (y0 + hr - 1) & MASK;
        int gx = (x0 + hc - 1) & MASK;
        uint4 v = *reinterpret_cast<const uint4*>(
            in + ((pbase + gy * HW + gx) * CH + cg * 8));
        *reinterpret_cast<uint4*>(&sAct[hp * 64 + ((cg ^ (hp & 7)) << 3)]) = v;
    }
    for (int g = t; g < 1152; g += 512) {
        int tap = g >> 7, s = (g >> 6) & 1, dl = g & 63;
        int ci0 = s * 32 + (dl >> 4) * 8;
        int co  = dl & 15;
        unsigned short o8[8];
#pragma unroll
        for (int j = 0; j < 8; j++)
            o8[j] = f2bf(w[(tap * 64 + ci0 + j) * 16 + co]);
        *reinterpret_cast<uint4*>(&sW[g * 8]) = *reinterpret_cast<uint4*>(o8);
    }
    for (int g = t; g < 19 * 35; g += 512) {
        int r = g / 35, c2 = g - r * 35;
        int gy = (y0 + r - 2) & MASK;
        int gx = (x0 + c2 - 2) & MASK;
        sC[g] = Cin[pbase + gy * HW + gx];
    }
    __syncthreads();

    f32x4 acc[4];
    {
        float bv = b[l15];
#pragma unroll
        for (int m = 0; m < 4; m++) acc[m] = (f32x4){bv, bv, bv, bv};
    }

    int pxb[4];
#pragma unroll
    for (int m = 0; m < 4; m++)
        pxb[m] = (2 * wid + (m >> 1)) * 34 + (m & 1) * 16 + l15;

    for (int tap = 0; tap < 9; tap++) {
        const int koff = (tap / 3) * 34 + (tap % 3);
#pragma unroll
        for (int s = 0; s < 2; s++) {
            bf16x8 bf = *reinterpret_cast<const bf16x8*>(
                &sW[((tap * 2 + s) << 9) + (lane << 3)]);
            const int o = s * 4 + l4;
#pragma unroll
            for (int m = 0; m < 4; m++) {
                int px  = pxb[m] + koff;
                int off = (px << 6) + (((o ^ px) & 7) << 3);
                bf16x8 af = *reinterpret_cast<const bf16x8*>(&sAct[off]);
                acc[m] = __builtin_amdgcn_mfma_f32_16x16x32_bf16(
                    af, bf, acc[m], 0, 0, 0);
            }
        }
    }

#pragma unroll
    for (int m = 0; m < 4; m++) {
        int py = 2 * wid + (m >> 1);
        int xb = (m & 1) * 16 + l4 * 4;
#pragma unroll
        for (int j = 0; j < 4; j++) {
            int xt = xb + j;
            float v = acc[m][j] * sC[(py + (l15 >> 2)) * 35 + xt + (l15 & 3)];
            v += __shfl_xor(v, 1);
            v += __shfl_xor(v, 2);
            v += __shfl_xor(v, 4);
            v += __shfl_xor(v, 8);
            if (l15 == 0)
                out[pbase + (y0 + py) * HW + x0 + xt] = v;
        }
    }
}

extern "C" void kernel_launch(void* const* d_in, const int* in_sizes, int n_in,
                              void* d_out, int out_size, void* d_ws, size_t ws_size,
                              hipStream_t stream)
{
    (void)in_sizes; (void)n_in; (void)out_size; (void)ws_size;
    const float* Cin  = (const float*)d_in[0];
    const float* vx   = (const float*)d_in[1];
    const float* vy   = (const float*)d_in[2];
    const float* w0   = (const float*)d_in[3];
    const float* b0   = (const float*)d_in[4];
    const float* w1   = (const float*)d_in[5];
    const float* b1   = (const float*)d_in[6];
    const float* w2   = (const float*)d_in[7];
    const float* b2   = (const float*)d_in[8];
    const float* w3   = (const float*)d_in[9];
    const float* b3   = (const float*)d_in[10];
    const float* w4   = (const float*)d_in[11];
    const float* b4   = (const float*)d_in[12];
    const float* wout = (const float*)d_in[13];
    const float* bout = (const float*)d_in[14];

    unsigned short* actA = (unsigned short*)d_ws;
    unsigned short* actB = actA + (size_t)8 * HW * HW * CH;

    // packed weights parked in d_out (2 MB; k_out_mfma fully rewrites d_out)
    unsigned short* wpk = (unsigned short*)d_out;   // 4 * 36864 ushorts = 288 KB

    dim3 block(512);
    dim3 grid0(HW / TX, HW / TY, 8);
    dim3 gridM(512);
    dim3 gridO(HW / 32, HW / 16, 8);

    k_pack    <<<36, block, 0, stream>>>(w1, w2, w3, w4, wpk);
    k_layer0  <<<grid0, block, 0, stream>>>(Cin, vx, vy, w0, b0, actA);
    k_mid_v4  <<<gridM, block, 0, stream>>>(actA, wpk + 0 * 36864, b1, actB);
    k_mid_v4  <<<gridM, block, 0, stream>>>(actB, wpk + 1 * 36864, b2, actA);
    k_mid_v4  <<<gridM, block, 0, stream>>>(actA, wpk + 2 * 36864, b3, actB);
    k_mid_v4  <<<gridM, block, 0, stream>>>(actB, wpk + 3 * 36864, b4, actA);
    k_out_mfma<<<gridO, block, 0, stream>>>(actA, wout, bout, Cin, (float*)d_out);
}

// Round 6
// 254.545 us; speedup vs baseline: 1.5185x; 1.0409x over previous
//
#include <hip/hip_runtime.h>
#include <hip/hip_bf16.h>

// StencilNet round 5: mids at 32x16 tile / 78KB LDS -> 2 blocks/CU so staging
// of one block overlaps compute of the other. Zero-barrier tap loop + packed
// weights (verified R4). Wave = 4 M-frags x 4 N-frags (k_out's verified
// pixel indexing). layer0 / k_out / k_pack unchanged.

#define HW   256
#define MASK 255
#define CH   64
#define TX   32
#define TY   16

typedef short bf16x8 __attribute__((ext_vector_type(8)));
typedef float f32x4  __attribute__((ext_vector_type(4)));

__device__ __forceinline__ float bf2f(unsigned short u) {
    return __uint_as_float(((unsigned int)u) << 16);
}
__device__ __forceinline__ unsigned short f2bf(float f) {
    unsigned int x = __float_as_uint(f);
    return (unsigned short)((x + 0x7fffu + ((x >> 16) & 1u)) >> 16);  // RNE
}

// ---- pack mid-layer weights into 16x16x32 B-frag layout (bf16) -------------
__global__ __launch_bounds__(512) void k_pack(
    const float* __restrict__ w1, const float* __restrict__ w2,
    const float* __restrict__ w3, const float* __restrict__ w4,
    unsigned short* __restrict__ dst)
{
    int g = blockIdx.x * 512 + threadIdx.x;
    if (g >= 4 * 4608) return;
    int L = g / 4608, r = g - L * 4608;
    const float* w = (L == 0) ? w1 : (L == 1) ? w2 : (L == 2) ? w3 : w4;
    int q = r >> 8, n = (r >> 6) & 3, l = r & 63;
    int tap = q >> 1, s = q & 1;
    int ci0 = s * 32 + ((l >> 4) << 3);
    int co  = n * 16 + (l & 15);
    unsigned short o8[8];
#pragma unroll
    for (int j = 0; j < 8; j++)
        o8[j] = f2bf(w[(tap * 64 + ci0 + j) * 64 + co]);
    *reinterpret_cast<uint4*>(dst + (size_t)g * 8) = *reinterpret_cast<uint4*>(o8);
}

// ---------------- Layer 0: [C,vx,vy] (3ch f32) -> 64ch bf16, ReLU -------------
__global__ __launch_bounds__(512) void k_layer0(
    const float* __restrict__ Cin, const float* __restrict__ vx,
    const float* __restrict__ vy, const float* __restrict__ w0,
    const float* __restrict__ b0, unsigned short* __restrict__ out)
{
    int t  = threadIdx.x;
    int lx = t & 31, ly = t >> 5;
    int x  = blockIdx.x * TX + lx;
    int y  = blockIdx.y * TY + ly;
    int bb = blockIdx.z;
    int pbase = bb * HW * HW;

    float a[27];
#pragma unroll
    for (int ky = 0; ky < 3; ky++) {
        int yy = (y + ky - 1) & MASK;
#pragma unroll
        for (int kx = 0; kx < 3; kx++) {
            int xx  = (x + kx - 1) & MASK;
            int idx = pbase + yy * HW + xx;
            a[(ky * 3 + kx) * 3 + 0] = Cin[idx];
            a[(ky * 3 + kx) * 3 + 1] = vx[idx];
            a[(ky * 3 + kx) * 3 + 2] = vy[idx];
        }
    }

    size_t obase = ((size_t)(pbase + y * HW + x)) * CH;
    for (int c4 = 0; c4 < 4; c4++) {
        float acc[16];
#pragma unroll
        for (int j = 0; j < 16; j++) acc[j] = b0[c4 * 16 + j];
#pragma unroll
        for (int k = 0; k < 27; k++) {
            float av = a[k];
            const float* wq = w0 + k * CH + c4 * 16;
#pragma unroll
            for (int j = 0; j < 16; j++) acc[j] = fmaf(av, wq[j], acc[j]);
        }
        unsigned short o[16];
#pragma unroll
        for (int j = 0; j < 16; j++) o[j] = f2bf(fmaxf(acc[j], 0.f));
        *reinterpret_cast<uint4*>(out + obase + c4 * 16)     = *reinterpret_cast<uint4*>(o);
        *reinterpret_cast<uint4*>(out + obase + c4 * 16 + 8) = *reinterpret_cast<uint4*>(o + 8);
    }
}

// ------------- Mid layers: 32x16 tile, 2 blocks/CU, zero-barrier tap loop ----
__global__ __launch_bounds__(512, 4) void k_mid_v5(
    const unsigned short* __restrict__ in,
    const unsigned short* __restrict__ wp,   // packed B-frags for this layer
    const float* __restrict__ b, unsigned short* __restrict__ out)
{
    __shared__ unsigned short sAct[18 * 34 * CH];  // 78336 B -> 2 blocks/CU

    const int t    = threadIdx.x;
    const int lane = t & 63;
    const int wid  = t >> 6;       // 0..7 -> tile rows 2*wid..2*wid+1
    const int l15  = lane & 15;
    const int l4   = lane >> 4;

    // bijective XCD-chunked swizzle: 1024 blocks = 8 chunks of 128
    const int bid = blockIdx.x;
    const int tid = (bid & 7) * 128 + (bid >> 3);
    const int bz  = tid >> 7;            // image 0..7
    const int rr  = tid & 127;           // 16(y) x 8(x) tiles, row-major
    const int y0  = (rr >> 3) * 16;
    const int x0  = (rr & 7) * 32;
    const size_t pbase = (size_t)bz * HW * HW;

    // ---- stage act halo 18x34x64 (bf16), XOR-swizzled (verified) ----
    for (int g = t; g < 18 * 34 * 8; g += 512) {
        int hp = g >> 3, cg = g & 7;
        int hr = hp / 34, hc = hp - hr * 34;
        int gy = (y0 + hr - 1) & MASK;
        int gx = (x0 + hc - 1) & MASK;
        uint4 v = *reinterpret_cast<const uint4*>(
            in + ((pbase + gy * HW + gx) * CH + cg * 8));
        *reinterpret_cast<uint4*>(&sAct[hp * 64 + ((cg ^ (hp & 7)) << 3)]) = v;
    }

    // prefetch B-frags for q=0 while staging completes
    bf16x8 bnx[4];
#pragma unroll
    for (int n = 0; n < 4; n++)
        bnx[n] = *reinterpret_cast<const bf16x8*>(wp + (size_t)(n * 512 + lane * 8));

    __syncthreads();   // the only barrier

    f32x4 acc[4][4];
#pragma unroll
    for (int m = 0; m < 4; m++)
#pragma unroll
        for (int n = 0; n < 4; n++) {
            float bv = b[n * 16 + l15];
            acc[m][n] = (f32x4){bv, bv, bv, bv};
        }

    int pxb[4];
#pragma unroll
    for (int m = 0; m < 4; m++)
        pxb[m] = (2 * wid + (m >> 1)) * 34 + (m & 1) * 16 + l15;

#pragma unroll
    for (int tap = 0; tap < 9; tap++) {
        const int koff = (tap / 3) * 34 + (tap % 3);
#pragma unroll
        for (int s = 0; s < 2; s++) {
            const int q = tap * 2 + s;
            bf16x8 bc[4];
#pragma unroll
            for (int n = 0; n < 4; n++) bc[n] = bnx[n];
            if (q < 17) {
#pragma unroll
                for (int n = 0; n < 4; n++)
                    bnx[n] = *reinterpret_cast<const bf16x8*>(
                        wp + (size_t)(((q + 1) * 4 + n) * 512 + lane * 8));
            }
            const int o = s * 4 + l4;
#pragma unroll
            for (int m = 0; m < 4; m++) {
                int px  = pxb[m] + koff;
                int off = (px << 6) + (((o ^ px) & 7) << 3);
                bf16x8 af = *reinterpret_cast<const bf16x8*>(&sAct[off]);
#pragma unroll
                for (int n = 0; n < 4; n++)
                    acc[m][n] = __builtin_amdgcn_mfma_f32_16x16x32_bf16(
                        af, bc[n], acc[m][n], 0, 0, 0);
            }
        }
    }

    // ---- epilogue: ReLU -> bf16 (verified R2 mapping) ----
#pragma unroll
    for (int m = 0; m < 4; m++) {
        int y = y0 + 2 * wid + (m >> 1);
        int x = x0 + (m & 1) * 16;
        unsigned short* pm = out + (pbase + (size_t)y * HW + x) * CH + (l4 << 8) + l15;
#pragma unroll
        for (int n = 0; n < 4; n++)
#pragma unroll
            for (int j = 0; j < 4; j++)
                pm[j * 64 + n * 16] = f2bf(fmaxf(acc[m][n][j], 0.f));
    }
}

// -------- Output layer MFMA: 64ch -> 16 coeffs + fused 4x4 stencil dot -------
__global__ __launch_bounds__(512, 2) void k_out_mfma(
    const unsigned short* __restrict__ in, const float* __restrict__ w,
    const float* __restrict__ b, const float* __restrict__ Cin,
    float* __restrict__ out)
{
    __shared__ unsigned short sAct[18 * 34 * CH];   // 78336 B
    __shared__ unsigned short sW[9 * 128 * 8];      // 18432 B
    __shared__ float sC[19 * 35];                   // 2660 B

    const int t    = threadIdx.x;
    const int lane = t & 63;
    const int wid  = t >> 6;
    const int l15  = lane & 15;
    const int l4   = lane >> 4;
    const int x0   = blockIdx.x * 32;
    const int y0   = blockIdx.y * 16;
    const size_t pbase = (size_t)blockIdx.z * HW * HW;

    for (int g = t; g < 18 * 34 * 8; g += 512) {
        int hp = g >> 3, cg = g & 7;
        int hr = hp / 34, hc = hp - hr * 34;
        int gy = (y0 + hr - 1) & MASK;
        int gx = (x0 + hc - 1) & MASK;
        uint4 v = *reinterpret_cast<const uint4*>(
            in + ((pbase + gy * HW + gx) * CH + cg * 8));
        *reinterpret_cast<uint4*>(&sAct[hp * 64 + ((cg ^ (hp & 7)) << 3)]) = v;
    }
    for (int g = t; g < 1152; g += 512) {
        int tap = g >> 7, s = (g >> 6) & 1, dl = g & 63;
        int ci0 = s * 32 + (dl >> 4) * 8;
        int co  = dl & 15;
        unsigned short o8[8];
#pragma unroll
        for (int j = 0; j < 8; j++)
            o8[j] = f2bf(w[(tap * 64 + ci0 + j) * 16 + co]);
        *reinterpret_cast<uint4*>(&sW[g * 8]) = *reinterpret_cast<uint4*>(o8);
    }
    for (int g = t; g < 19 * 35; g += 512) {
        int r = g / 35, c2 = g - r * 35;
        int gy = (y0 + r - 2) & MASK;
        int gx = (x0 + c2 - 2) & MASK;
        sC[g] = Cin[pbase + gy * HW + gx];
    }
    __syncthreads();

    f32x4 acc[4];
    {
        float bv = b[l15];
#pragma unroll
        for (int m = 0; m < 4; m++) acc[m] = (f32x4){bv, bv, bv, bv};
    }

    int pxb[4];
#pragma unroll
    for (int m = 0; m < 4; m++)
        pxb[m] = (2 * wid + (m >> 1)) * 34 + (m & 1) * 16 + l15;

    for (int tap = 0; tap < 9; tap++) {
        const int koff = (tap / 3) * 34 + (tap % 3);
#pragma unroll
        for (int s = 0; s < 2; s++) {
            bf16x8 bf = *reinterpret_cast<const bf16x8*>(
                &sW[((tap * 2 + s) << 9) + (lane << 3)]);
            const int o = s * 4 + l4;
#pragma unroll
            for (int m = 0; m < 4; m++) {
                int px  = pxb[m] + koff;
                int off = (px << 6) + (((o ^ px) & 7) << 3);
                bf16x8 af = *reinterpret_cast<const bf16x8*>(&sAct[off]);
                acc[m] = __builtin_amdgcn_mfma_f32_16x16x32_bf16(
                    af, bf, acc[m], 0, 0, 0);
            }
        }
    }

#pragma unroll
    for (int m = 0; m < 4; m++) {
        int py = 2 * wid + (m >> 1);
        int xb = (m & 1) * 16 + l4 * 4;
#pragma unroll
        for (int j = 0; j < 4; j++) {
            int xt = xb + j;
            float v = acc[m][j] * sC[(py + (l15 >> 2)) * 35 + xt + (l15 & 3)];
            v += __shfl_xor(v, 1);
            v += __shfl_xor(v, 2);
            v += __shfl_xor(v, 4);
            v += __shfl_xor(v, 8);
            if (l15 == 0)
                out[pbase + (y0 + py) * HW + x0 + xt] = v;
        }
    }
}

extern "C" void kernel_launch(void* const* d_in, const int* in_sizes, int n_in,
                              void* d_out, int out_size, void* d_ws, size_t ws_size,
                              hipStream_t stream)
{
    (void)in_sizes; (void)n_in; (void)out_size; (void)ws_size;
    const float* Cin  = (const float*)d_in[0];
    const float* vx   = (const float*)d_in[1];
    const float* vy   = (const float*)d_in[2];
    const float* w0   = (const float*)d_in[3];
    const float* b0   = (const float*)d_in[4];
    const float* w1   = (const float*)d_in[5];
    const float* b1   = (const float*)d_in[6];
    const float* w2   = (const float*)d_in[7];
    const float* b2   = (const float*)d_in[8];
    const float* w3   = (const float*)d_in[9];
    const float* b3   = (const float*)d_in[10];
    const float* w4   = (const float*)d_in[11];
    const float* b4   = (const float*)d_in[12];
    const float* wout = (const float*)d_in[13];
    const float* bout = (const float*)d_in[14];

    unsigned short* actA = (unsigned short*)d_ws;
    unsigned short* actB = actA + (size_t)8 * HW * HW * CH;

    unsigned short* wpk = (unsigned short*)d_out;   // parked; k_out rewrites

    dim3 block(512);
    dim3 grid0(HW / TX, HW / TY, 8);
    dim3 gridM(1024);
    dim3 gridO(HW / 32, HW / 16, 8);

    k_pack    <<<36, block, 0, stream>>>(w1, w2, w3, w4, wpk);
    k_layer0  <<<grid0, block, 0, stream>>>(Cin, vx, vy, w0, b0, actA);
    k_mid_v5  <<<gridM, block, 0, stream>>>(actA, wpk + 0 * 36864, b1, actB);
    k_mid_v5  <<<gridM, block, 0, stream>>>(actB, wpk + 1 * 36864, b2, actA);
    k_mid_v5  <<<gridM, block, 0, stream>>>(actA, wpk + 2 * 36864, b3, actB);
    k_mid_v5  <<<gridM, block, 0, stream>>>(actB, wpk + 3 * 36864, b4, actA);
    k_out_mfma<<<gridO, block, 0, stream>>>(actA, wout, bout, Cin, (float*)d_out);
}